// Round 9
// baseline (477.916 us; speedup 1.0000x reference)
//
#include <hip/hip_runtime.h>
#include <stdint.h>

// y[8192,4096] = x[8192,4096] @ W[4096,4096]^T + bias
// W from codebook[4096,8] gathered by indices[2M].
// R13: occupancy restructure — 2 WGs/CU (TLP replaces failed ILP attempts
//      R10-R12; MfmaUtil pinned ~50% with 1 WG/CU convoy).
//      Tile 256x128, BK=32, 256 threads (4 waves 2m x 2n, wave = 128x64,
//      acc[8][4] unchanged). LDS = 3-slot ring (A 16KiB, B 8KiB units) =
//      72 KiB/WG -> 2 WGs/CU; one frag set (48 VGPR) -> 256 regs/wave holds
//      2 waves/SIMD. Phase = [STAGE t+2 (6 loads)] [12 ds_read_b128]
//      [32 MFMA] [vmcnt(6)] [barrier]; counted vmcnt, 2-phase cover.
//      Same row-width-32 LDS geometry => same verified swizzle, 0 conflicts.

#define M_DIM 8192
#define N_DIM 4096
#define K_DIM 4096
#define BM 256
#define BN 128
#define BK 32
#define NT (K_DIM / BK)                       // 128 K-steps
#define AUNIT 8192                            // A slot elems (256x32)
#define BUNIT 4096                            // B slot elems (128x32)
#define NUM_W_BLOCKS 2097152                  // 4096*4096/8
#define W_WGS (NUM_W_BLOCKS / 256)            // 8192 WGs for W dequant
#define X_WGS ((M_DIM * K_DIM / 4) / 256)     // 32768 WGs, one float4/thread

typedef __attribute__((ext_vector_type(8))) __bf16 bf16x8;
typedef __attribute__((ext_vector_type(4))) float floatx4;
typedef __attribute__((ext_vector_type(2))) unsigned int uintx2;

// fp32 -> bf16 round-to-nearest-even (finite inputs)
__device__ __forceinline__ unsigned int f2bf(float f) {
    unsigned int u = __builtin_bit_cast(unsigned int, f);
    u += 0x7fffu + ((u >> 16) & 1u);
    return u >> 16;
}

// ------------- fused prep: W dequant-gather + x fp32->bf16 -------------
__global__ __launch_bounds__(256) void prep_kernel(
    const float* __restrict__ cb, const int* __restrict__ idx,
    uint4* __restrict__ W, const floatx4* __restrict__ x,
    uintx2* __restrict__ xb) {
    const int wg = blockIdx.x;
    if (wg < W_WGS) {
        const int b = wg * 256 + threadIdx.x;
        const int id = __builtin_nontemporal_load(idx + b);
        const float4* s = (const float4*)(cb + ((size_t)id << 3));
        const float4 a = s[0];
        const float4 c = s[1];
        uint4 o;
        o.x = f2bf(a.x) | (f2bf(a.y) << 16);
        o.y = f2bf(a.z) | (f2bf(a.w) << 16);
        o.z = f2bf(c.x) | (f2bf(c.y) << 16);
        o.w = f2bf(c.z) | (f2bf(c.w) << 16);
        W[b] = o;
    } else {
        const size_t t = (size_t)(wg - W_WGS) * 256 + threadIdx.x;
        const floatx4 a = __builtin_nontemporal_load(x + t);
        uintx2 o;
        o.x = f2bf(a.x) | (f2bf(a.y) << 16);
        o.y = f2bf(a.z) | (f2bf(a.w) << 16);
        xb[t] = o;
    }
}

// ---------------- async global -> LDS, 16B per lane ----------------
__device__ __forceinline__ void async_copy16(const __bf16* g, __bf16* s) {
    __builtin_amdgcn_global_load_lds(
        (const __attribute__((address_space(1))) unsigned int*)(uintptr_t)g,
        (__attribute__((address_space(3))) unsigned int*)(uintptr_t)s,
        16, 0, 0);
}

// Stage A unit (256 rows x 32 bf16 = 16 KiB): 4 rounds of 64 rows.
#define STAGE_A(koff, aoff)                                                \
    do {                                                                   \
        const __bf16* g_ = gA + (koff);                                    \
        async_copy16(g_, sA + (aoff) + wave512);                           \
        async_copy16(g_ + (size_t)64 * K_DIM, sA + (aoff) + 2048 + wave512); \
        async_copy16(g_ + (size_t)128 * K_DIM, sA + (aoff) + 4096 + wave512); \
        async_copy16(g_ + (size_t)192 * K_DIM, sA + (aoff) + 6144 + wave512); \
    } while (0)
// Stage B unit (128 rows x 32 bf16 = 8 KiB): 2 rounds of 64 rows.
#define STAGE_B(koff, boff)                                                \
    do {                                                                   \
        const __bf16* g_ = gB + (koff);                                    \
        async_copy16(g_, sB + (boff) + wave512);                           \
        async_copy16(g_ + (size_t)64 * K_DIM, sB + (boff) + 2048 + wave512); \
    } while (0)

// ---------------- GEMM: C[M][N] = A[M][K] * B[N][K]^T + bias ----------------
// 256 threads = 4 waves (2m x 2n); wave owns 128x64 output = acc[8][4] f32x4.
// LDS: 3-slot rings sA[3][8192], sB[3][4096] (72 KiB) -> 2 WGs/CU.
// Per K-step: [STAGE t+2 -> slot nx2 (6 loads)] [af x8 + bf x4 ds_read_b128]
// [32 MFMA] [vmcnt(6): drain t+1 (issued 2 phases ago)] [s_barrier] [rotate].
// WAR: slot nx2 = slot(t-1), all reads of t-1 done before barrier(t-1).
// RAW: slot nxt staged at phase t-1, drained by end-of-phase-t vmcnt(6).
__global__ __launch_bounds__(256, 2) void gemm_bt_kernel(
    const __bf16* __restrict__ A,   // [M][K] bf16
    const __bf16* __restrict__ B,   // [N][K] bf16
    const float* __restrict__ bias, // [N]
    float* __restrict__ C) {        // [M][N] fp32
    __shared__ __align__(16) __bf16 sA[3 * AUNIT];   // 48 KiB
    __shared__ __align__(16) __bf16 sB[3 * BUNIT];   // 24 KiB

    const int tid = threadIdx.x;
    const int wave = tid >> 6;
    const int lane = tid & 63;
    const int wr = wave >> 1;            // 0..1  (M half of tile)
    const int wc = wave & 1;             // 0..1  (N half of tile)

    // XCD-chunked mapping: grid 32m x 32n tiles; XCD owns 8m x 16n (128 WGs),
    // co-resident half = 8m x 8n (64 WGs = 32 CUs x 2 WGs). Bijective.
    const int flat = blockIdx.x;
    const int xcd = flat & 7;
    const int q = flat >> 3;             // 0..127
    const int sq = q & 63;
    const int mi = (xcd & 3) * 8 + (sq & 7);
    const int ni = (xcd >> 2) * 16 + (q >> 6) * 8 + (sq >> 3);
    const int m0 = mi * BM;
    const int n0 = ni * BN;

    // staging: thread t covers row = t>>2 (+64 per round), phys chunk t&3;
    // fetch logical chunk c = p ^ ((row>>1)&3) (involution, invariant +64)
    const int srow = tid >> 2;
    const int schunk = ((tid & 3) ^ ((srow >> 1) & 3)) << 3;
    const __bf16* gA = A + (size_t)(m0 + srow) * K_DIM + schunk;
    const __bf16* gB = B + (size_t)(n0 + srow) * K_DIM + schunk;
    const int wave512 = wave << 9;

    // fragment reads: lane holds X[row = base + fr][k = (lane>>4)*8 + j];
    // physical chunk = (lane>>4) ^ ((fr>>1)&3). Row width 32 elems (64 B),
    // identical geometry to the verified 0-conflict layout.
    const int fr = lane & 15;
    const int phys8 = (((lane >> 4) ^ ((fr >> 1) & 3)) << 3);
    const int aBase = (wr * 128 + fr) * 32 + phys8;   // + i*512, i=0..7
    const int bBase = (wc * 64 + fr) * 32 + phys8;    // + j*512, j=0..3

    floatx4 acc[8][4] = {};

    // ---- prologue: stage t0 -> slot0, t1 -> slot1 ----
    STAGE_A(0, 0);
    STAGE_B(0, 0);
    STAGE_A(32, AUNIT);
    STAGE_B(32, BUNIT);
    asm volatile("s_waitcnt vmcnt(6)" ::: "memory");  // t0 (6 loads) landed
    __builtin_amdgcn_s_barrier();

    int cur = 0, nxt = 1, nx2 = 2;       // slot indices (wave-uniform)

    for (int t = 0; t < NT; ++t) {
        // stage t+2 into slot nx2 (= slot of t-1; readers done @barrier(t-1))
        if (t + 2 < NT) {
            STAGE_A((t + 2) * BK, nx2 * AUNIT);
            STAGE_B((t + 2) * BK, nx2 * BUNIT);
        }

        const __bf16* pA = sA + cur * AUNIT;
        const __bf16* pB = sB + cur * BUNIT;
        bf16x8 af[8], bf4[4];
#pragma unroll
        for (int i = 0; i < 8; ++i)
            af[i] = *(const bf16x8*)(pA + aBase + i * 512);
#pragma unroll
        for (int j = 0; j < 4; ++j)
            bf4[j] = *(const bf16x8*)(pB + bBase + j * 512);

        __builtin_amdgcn_s_setprio(1);
#pragma unroll
        for (int i = 0; i < 8; ++i)
#pragma unroll
            for (int j = 0; j < 4; ++j)
                acc[i][j] = __builtin_amdgcn_mfma_f32_16x16x32_bf16(
                    af[i], bf4[j], acc[i][j], 0, 0, 0);
        __builtin_amdgcn_s_setprio(0);

        // drain t+1 (staged 2 phases ago); keep t+2's 6 loads in flight
        if (t + 2 < NT)
            asm volatile("s_waitcnt vmcnt(6)" ::: "memory");
        else
            asm volatile("s_waitcnt vmcnt(0)" ::: "memory");
        __builtin_amdgcn_s_barrier();

        const int tmp = cur; cur = nxt; nxt = nx2; nx2 = tmp;
    }

    // Epilogue. C/D layout: col = lane&15, row = (lane>>4)*4 + reg
    const int crow = (lane >> 4) * 4;
    const int ccol = lane & 15;
#pragma unroll
    for (int j = 0; j < 4; ++j) {
        const int n = n0 + wc * 64 + j * 16 + ccol;
        const float bv = bias[n];
#pragma unroll
        for (int i = 0; i < 8; ++i) {
            const int m = m0 + wr * 128 + i * 16 + crow;
            float* cp = C + (size_t)m * N_DIM + n;
#pragma unroll
            for (int r = 0; r < 4; ++r)
                __builtin_nontemporal_store(acc[i][j][r] + bv,
                                            cp + (size_t)r * N_DIM);
        }
    }
}

extern "C" void kernel_launch(void* const* d_in, const int* in_sizes, int n_in,
                              void* d_out, int out_size, void* d_ws, size_t ws_size,
                              hipStream_t stream) {
    const float* x    = (const float*)d_in[0];   // [4,2048,4096] fp32
    const float* cb   = (const float*)d_in[1];   // [4096,8] fp32
    const int*   idx  = (const int*)d_in[2];     // [2M]
    const float* bias = (const float*)d_in[3];   // [4096]
    float* out = (float*)d_out;                  // [4,2048,4096] fp32

    // workspace layout: W_bf16 (32 MB) | x_bf16 (64 MB)
    __bf16* Wb = (__bf16*)d_ws;
    __bf16* Xb = (__bf16*)((char*)d_ws + (size_t)N_DIM * K_DIM * sizeof(__bf16));

    prep_kernel<<<W_WGS + X_WGS, 256, 0, stream>>>(
        cb, idx, (uint4*)Wb, (const floatx4*)x, (uintx2*)Xb);

    dim3 grid((M_DIM / BM) * (N_DIM / BN));  // 1024 WGs, XCD-chunked
    gemm_bt_kernel<<<grid, 256, 0, stream>>>(Xb, Wb, bias, out);
}